// Round 18
// baseline (466.097 us; speedup 1.0000x reference)
//
#include <hip/hip_runtime.h>
#include <hip/hip_fp16.h>

#define NB 8
#define NC 512
#define NK 128   // key_dim C2
#define NP 128   // positions per attention row (H = W = 128)
#define NHW 16384

typedef unsigned short u16;
typedef unsigned int u32;
typedef float f32x4 __attribute__((ext_vector_type(4)));
typedef _Float16 f16x8 __attribute__((ext_vector_type(8)));

__device__ __forceinline__ u16 f2h(float f) { return __half_as_ushort(__float2half(f)); }
__device__ __forceinline__ float h2f(u16 u) { return __half2float(__ushort_as_half(u)); }

// ---------------- weights fp32 -> fp16, concatenated [wq;wk] row-major ----------------
__global__ __launch_bounds__(256) void wconv_kernel(const float* __restrict__ wq,
                                                    const float* __restrict__ wk,
                                                    u16* __restrict__ wh) {
    int row = blockIdx.x;  // 0..255
    const float* src = (row < 128) ? (wq + (size_t)row * NC) : (wk + (size_t)(row - 128) * NC);
    int t = threadIdx.x;
    float2 v = *(const float2*)(src + t * 2);
    ushort2 o; o.x = f2h(v.x); o.y = f2h(v.y);
    *(ushort2*)(wh + (size_t)row * NC + t * 2) = o;
}

// ---------------- x fp32 [plane][h][w] -> xt fp16 [plane][w][h] ----------------
__global__ __launch_bounds__(256) void convtr_kernel(const float* __restrict__ x,
                                                     u16* __restrict__ xt) {
    __shared__ u16 ts[32][36];
    int plane = blockIdx.y;
    int tile  = blockIdx.x;
    int h0 = (tile >> 2) * 32, w0 = (tile & 3) * 32;
    const float* ip = x + (size_t)plane * NHW;
    u16* op = xt + (size_t)plane * NHW;
    int r  = threadIdx.x >> 3;
    int c4 = (threadIdx.x & 7) * 4;
    float4 v = *(const float4*)(ip + (h0 + r) * NP + w0 + c4);
    ts[r][c4 + 0] = f2h(v.x); ts[r][c4 + 1] = f2h(v.y);
    ts[r][c4 + 2] = f2h(v.z); ts[r][c4 + 3] = f2h(v.w);
    __syncthreads();
    ushort4 o;
    o.x = ts[c4 + 0][r]; o.y = ts[c4 + 1][r]; o.z = ts[c4 + 2][r]; o.w = ts[c4 + 3][r];
    *(ushort4*)(op + (w0 + r) * NP + h0 + c4) = o;
}

// ---------------- fused q+k projection via MFMA (v3, unchanged) ----------------
#define XROW 40   // u16 stride of one p-row (80 B, 16B-aligned)
__device__ __forceinline__ int xt2_off(int p, int cw) {
    int sw = ((p >> 3) & 3) << 2;
    return p * XROW + 2 * (cw ^ sw);
}

__global__ __launch_bounds__(256, 3) void proj_kernel(const float* __restrict__ x,
                                                      const u16* __restrict__ wh,
                                                      const float* __restrict__ bq,
                                                      const float* __restrict__ bk,
                                                      u16* __restrict__ q,
                                                      u16* __restrict__ k) {
    __shared__ __align__(16) u16 smem[9216];
    int b  = blockIdx.y;
    int p0 = blockIdx.x * 64;
    int tid = threadIdx.x;
    int lane = tid & 63, w = tid >> 6;
    int ln = lane & 15, g = lane >> 4;

    float biasv[4];
#pragma unroll
    for (int nf = 0; nf < 4; nf++) {
        int oc = w * 64 + nf * 16 + ln;
        biasv[nf] = (oc < 128) ? bq[oc] : bk[oc - 128];
    }

    f32x4 acc[4][4];
#pragma unroll
    for (int mf = 0; mf < 4; mf++)
#pragma unroll
        for (int nf = 0; nf < 4; nf++) acc[mf][nf] = 0.0f;

    int si  = tid >> 4;          // 0..15
    int spx = (tid & 15) * 4;

#define STAGE(buf, c0)                                                                  \
    {                                                                                   \
        const float* xa = x + ((size_t)(b * NC + (c0) + 2 * si)) * NHW + p0 + spx;      \
        const float* xb = xa + NHW;                                                     \
        float4 a0 = *(const float4*)xa;                                                 \
        float4 b0 = *(const float4*)xb;                                                 \
        float av[4] = {a0.x, a0.y, a0.z, a0.w};                                         \
        float bv[4] = {b0.x, b0.y, b0.z, b0.w};                                         \
        _Pragma("unroll") for (int j = 0; j < 4; j++) {                                 \
            ushort2 pk;                                                                 \
            pk.x = f2h(av[j]); pk.y = f2h(bv[j]);                                       \
            *(ushort2*)&smem[(buf) * 2560 + xt2_off(spx + j, si)] = pk;                 \
        }                                                                               \
    }

    STAGE(0, 0);
    __syncthreads();
    for (int t = 0; t < 16; ++t) {
        int c0 = t * 32;
        if (t < 15) STAGE((t + 1) & 1, c0 + 32);
        f16x8 bf[4];
#pragma unroll
        for (int nf = 0; nf < 4; nf++)
            bf[nf] = *(const f16x8*)&wh[((size_t)(w * 64 + nf * 16 + ln)) * NC + c0 + g * 8];
        f16x8 af[4];
#pragma unroll
        for (int mf = 0; mf < 4; mf++)
            af[mf] = *(const f16x8*)&smem[(t & 1) * 2560 + xt2_off(mf * 16 + ln, g * 4)];
#pragma unroll
        for (int mf = 0; mf < 4; mf++)
#pragma unroll
            for (int nf = 0; nf < 4; nf++)
                acc[mf][nf] = __builtin_amdgcn_mfma_f32_16x16x32_f16(af[mf], bf[nf], acc[mf][nf], 0, 0, 0);
        __syncthreads();
    }
#undef STAGE

#pragma unroll
    for (int pass = 0; pass < 2; pass++) {
        if ((w >> 1) == pass) {
            int colbase = (w & 1) * 64;
#pragma unroll
            for (int mf = 0; mf < 4; mf++)
#pragma unroll
                for (int nf = 0; nf < 4; nf++)
#pragma unroll
                    for (int rg = 0; rg < 4; rg++) {
                        int p = mf * 16 + g * 4 + rg;
                        smem[p * 136 + colbase + nf * 16 + ln] = f2h(acc[mf][nf][rg] + biasv[nf]);
                    }
        }
        __syncthreads();
        {
            int p = tid >> 2, seg = tid & 3;
            u16* dst = (pass == 0 ? q : k) + ((size_t)(b * NHW + p0 + p)) * NK + seg * 32;
            const u16* srcl = &smem[p * 136 + seg * 32];
            *(uint4*)(dst)     = *(const uint4*)(srcl);
            *(uint4*)(dst + 8) = *(const uint4*)(srcl + 8);
            *(uint4*)(dst + 16) = *(const uint4*)(srcl + 16);
            *(uint4*)(dst + 24) = *(const uint4*)(srcl + 24);
        }
        __syncthreads();
    }
}

// ---------------- merged axis attention — 512 threads, K-in-LDS (r16), PV c-tile = 128 ----------------
// zp=0: W-pass — r=h, Q/K rows contiguous, V = x fp32 (cvt), out = owh fp16 (WOH=1) or outw fp32
// zp=1: H-pass — r=w, Q/K rows strided,   V = xt fp16,       out = oht fp16
// E: wave (wj=w>>2, wi=w&3) owns 64j x 32i.  PV: wave (wc=w>>2, wi2=w&3) owns 64c x 32i of a 128c tile.
template <int WOH>
__global__ __launch_bounds__(512) void attn_kernel(const u16* __restrict__ q,
                                                   const u16* __restrict__ k,
                                                   const float* __restrict__ x,
                                                   const u16* __restrict__ xt,
                                                   u16* __restrict__ owh,
                                                   u16* __restrict__ oht,
                                                   float* __restrict__ outw) {
    __shared__ __align__(16) u16 smem[2 * 128 * 136];
    __shared__ float redmax[256];
    __shared__ float redsum[256];
    u16* Ks = smem;
    u16* Qs = smem + 128 * 136;
    u16* Al = smem;
    u16* Vl = smem + 128 * 136;   // 128 x 136 tile (full dead-Ks... actually Qs region is Al; Vl = old Qs region)

    int r = blockIdx.x, b = blockIdx.y;
    int zp = blockIdx.z;   // 0 = W-pass, 1 = H-pass
    int tid = threadIdx.x;
    int lane = tid & 63, w = tid >> 6;
    int ln = lane & 15, g = lane >> 4;

    const size_t base = zp ? ((size_t)b * NHW + r) * NK : ((size_t)b * NHW + (size_t)r * NP) * NK;
    const int qrs = zp ? NP * NK : NK;

    // stage Q,K position-major [j][c]: 512 threads, 64B per matrix each
    {
        int j = tid >> 2, hf = tid & 3;
        const u16* qp2 = q + base + (size_t)j * qrs + hf * 32;
        const u16* kp2 = k + base + (size_t)j * qrs + hf * 32;
#pragma unroll
        for (int e = 0; e < 4; e++) {
            *(uint4*)&Qs[j * 136 + hf * 32 + e * 8] = *(const uint4*)(qp2 + e * 8);
            *(uint4*)&Ks[j * 136 + hf * 32 + e * 8] = *(const uint4*)(kp2 + e * 8);
        }
    }
    __syncthreads();

    // ---- E^T: wave (wj, wi), tile 64j x 32i ----
    int wj = w >> 2, wi = w & 3;
    f32x4 e[4][2];
#pragma unroll
    for (int mf = 0; mf < 4; mf++)
#pragma unroll
        for (int nf = 0; nf < 2; nf++) e[mf][nf] = 0.0f;
#pragma unroll
    for (int ks = 0; ks < 4; ks++) {
        f16x8 qa[4], kb[2];
#pragma unroll
        for (int mf = 0; mf < 4; mf++)
            qa[mf] = *(const f16x8*)&Qs[(wj * 64 + mf * 16 + ln) * 136 + ks * 32 + g * 8];
#pragma unroll
        for (int nf = 0; nf < 2; nf++)
            kb[nf] = *(const f16x8*)&Ks[(wi * 32 + nf * 16 + ln) * 136 + ks * 32 + g * 8];
#pragma unroll
        for (int mf = 0; mf < 4; mf++)
#pragma unroll
            for (int nf = 0; nf < 2; nf++)
                e[mf][nf] = __builtin_amdgcn_mfma_f32_16x16x32_f16(qa[mf], kb[nf], e[mf][nf], 0, 0, 0);
    }

    // ---- softmax over j; lane's i columns: i = wi*32 + nf*16 + ln ----
    float pm[2];
#pragma unroll
    for (int nf = 0; nf < 2; nf++) {
        pm[nf] = -3.0e38f;
#pragma unroll
        for (int mf = 0; mf < 4; mf++)
#pragma unroll
            for (int rg = 0; rg < 4; rg++) pm[nf] = fmaxf(pm[nf], e[mf][nf][rg]);
        pm[nf] = fmaxf(pm[nf], __shfl_xor(pm[nf], 16));
        pm[nf] = fmaxf(pm[nf], __shfl_xor(pm[nf], 32));
    }
    if (g == 0) {
#pragma unroll
        for (int nf = 0; nf < 2; nf++) redmax[wj * 128 + wi * 32 + nf * 16 + ln] = pm[nf];
    }
    __syncthreads();
    float fm[2];
#pragma unroll
    for (int nf = 0; nf < 2; nf++) {
        int i = wi * 32 + nf * 16 + ln;
        fm[nf] = fmaxf(redmax[i], redmax[128 + i]);
    }
    float ps[2] = {0.f, 0.f};
#pragma unroll
    for (int mf = 0; mf < 4; mf++)
#pragma unroll
        for (int nf = 0; nf < 2; nf++)
#pragma unroll
            for (int rg = 0; rg < 4; rg++) {
                float v = __expf(e[mf][nf][rg] - fm[nf]);
                e[mf][nf][rg] = v;
                ps[nf] += v;
            }
#pragma unroll
    for (int nf = 0; nf < 2; nf++) {
        ps[nf] += __shfl_xor(ps[nf], 16);
        ps[nf] += __shfl_xor(ps[nf], 32);
    }
    if (g == 0) {
#pragma unroll
        for (int nf = 0; nf < 2; nf++) redsum[wj * 128 + wi * 32 + nf * 16 + ln] = ps[nf];
    }
    __syncthreads();
    float ivs[2];
#pragma unroll
    for (int nf = 0; nf < 2; nf++) {
        int i = wi * 32 + nf * 16 + ln;
        ivs[nf] = 1.0f / (redsum[i] + redsum[128 + i]);
    }
    // pack A fp16 into Al[i][j] (region A; all cross-wave Qs reads completed before redmax barrier)
#pragma unroll
    for (int mf = 0; mf < 4; mf++)
#pragma unroll
        for (int nf = 0; nf < 2; nf++) {
            ushort4 pk;
            pk.x = f2h(e[mf][nf][0] * ivs[nf]);
            pk.y = f2h(e[mf][nf][1] * ivs[nf]);
            pk.z = f2h(e[mf][nf][2] * ivs[nf]);
            pk.w = f2h(e[mf][nf][3] * ivs[nf]);
            *(ushort4*)&Al[(wi * 32 + nf * 16 + ln) * 136 + wj * 64 + mf * 16 + g * 4] = pk;
        }
    __syncthreads();

    // ---- PV: c-tile = 128 (4 tiles, 8 barriers total); wave (wc=w>>2, wi2=w&3) owns 64c x 32i ----
    int wc = w >> 2, wi2 = w & 3;
    f16x8 bfr[2][4];
#pragma unroll
    for (int nf2 = 0; nf2 < 2; nf2++)
#pragma unroll
        for (int js = 0; js < 4; js++)
            bfr[nf2][js] = *(const f16x8*)&Al[(wi2 * 32 + nf2 * 16 + ln) * 136 + js * 32 + g * 8];

    int cc = tid >> 2, ch = (tid & 3) * 32;   // 128 rows x 128 cols, 32 u16/thread
    u16 vh[32];
#define LOADV(c0)                                                                           \
    {                                                                                       \
        if (zp) {                                                                           \
            const u16* vn = xt + ((size_t)(b * NC + (c0) + cc)) * NHW + (size_t)r * NP + ch;\
            _Pragma("unroll") for (int e2 = 0; e2 < 4; e2++)                                \
                *(uint4*)&vh[e2 * 8] = *(const uint4*)(vn + e2 * 8);                        \
        } else {                                                                            \
            const float* vn = x + ((size_t)(b * NC + (c0) + cc)) * NHW + (size_t)r * NP + ch;\
            _Pragma("unroll") for (int e2 = 0; e2 < 8; e2++) {                              \
                float4 vv = *(const float4*)(vn + e2 * 4);                                  \
                vh[e2 * 4 + 0] = f2h(vv.x); vh[e2 * 4 + 1] = f2h(vv.y);                     \
                vh[e2 * 4 + 2] = f2h(vv.z); vh[e2 * 4 + 3] = f2h(vv.w);                     \
            }                                                                               \
        }                                                                                   \
    }

    LOADV(0);
    for (int c0 = 0; c0 < NC; c0 += 128) {
#pragma unroll
        for (int e2 = 0; e2 < 4; e2++)
            *(uint4*)&Vl[cc * 136 + ch + e2 * 8] = *(uint4*)&vh[e2 * 8];
        __syncthreads();
        if (c0 + 128 < NC) LOADV(c0 + 128);   // hide next tile's HBM latency under MFMA
        f32x4 o[4][2];
#pragma unroll
        for (int mf2 = 0; mf2 < 4; mf2++)
#pragma unroll
            for (int nf2 = 0; nf2 < 2; nf2++) o[mf2][nf2] = 0.0f;
#pragma unroll
        for (int js = 0; js < 4; js++) {
            f16x8 va[4];
#pragma unroll
            for (int mf2 = 0; mf2 < 4; mf2++)
                va[mf2] = *(const f16x8*)&Vl[(wc * 64 + mf2 * 16 + ln) * 136 + js * 32 + g * 8];
#pragma unroll
            for (int mf2 = 0; mf2 < 4; mf2++)
#pragma unroll
                for (int nf2 = 0; nf2 < 2; nf2++)
                    o[mf2][nf2] = __builtin_amdgcn_mfma_f32_16x16x32_f16(va[mf2], bfr[nf2][js], o[mf2][nf2], 0, 0, 0);
        }
#pragma unroll
        for (int mf2 = 0; mf2 < 4; mf2++)
#pragma unroll
            for (int nf2 = 0; nf2 < 2; nf2++)
#pragma unroll
                for (int rg = 0; rg < 4; rg++) {
                    int ci = c0 + wc * 64 + mf2 * 16 + g * 4 + rg;
                    int ii = wi2 * 32 + nf2 * 16 + ln;
                    size_t oa = ((size_t)(b * NC + ci)) * NHW + (size_t)r * NP + ii;
                    if (zp)           oht[oa] = f2h(o[mf2][nf2][rg]);
                    else if (WOH)     owh[oa] = f2h(o[mf2][nf2][rg]);
                    else              outw[oa] = o[mf2][nf2][rg];
                }
        __syncthreads();
    }
#undef LOADV
}

// ---------------- out[plane][h][w] = owh[plane][h][w] + oht[plane][w][h] ----------------
__global__ __launch_bounds__(256) void combine_kernel(const u16* __restrict__ owh,
                                                      const u16* __restrict__ oht,
                                                      float* __restrict__ out) {
    __shared__ u16 ts[32][36];
    int plane = blockIdx.y;
    int tile  = blockIdx.x;
    int h0 = (tile >> 2) * 32, w0 = (tile & 3) * 32;
    int r  = threadIdx.x >> 3;
    int c4 = (threadIdx.x & 7) * 4;
    ushort4 v = *(const ushort4*)(oht + (size_t)plane * NHW + (w0 + r) * NP + h0 + c4);
    ts[r][c4 + 0] = v.x; ts[r][c4 + 1] = v.y; ts[r][c4 + 2] = v.z; ts[r][c4 + 3] = v.w;
    __syncthreads();
    ushort4 a = *(const ushort4*)(owh + (size_t)plane * NHW + (h0 + r) * NP + w0 + c4);
    float4 o;
    o.x = h2f(a.x) + h2f(ts[c4 + 0][r]);
    o.y = h2f(a.y) + h2f(ts[c4 + 1][r]);
    o.z = h2f(a.z) + h2f(ts[c4 + 2][r]);
    o.w = h2f(a.w) + h2f(ts[c4 + 3][r]);
    *(float4*)(out + (size_t)plane * NHW + (h0 + r) * NP + w0 + c4) = o;
}

// ---------------- fallback: out[plane][h][w] += oht[plane][w][h] (fp16 -> fp32 RMW) ----------------
__global__ __launch_bounds__(256) void addtr_kernel(const u16* __restrict__ oht,
                                                    float* __restrict__ out) {
    __shared__ u16 ts[32][36];
    int plane = blockIdx.y;
    int tile  = blockIdx.x;
    int h0 = (tile >> 2) * 32, w0 = (tile & 3) * 32;
    int r  = threadIdx.x >> 3;
    int c4 = (threadIdx.x & 7) * 4;
    ushort4 v = *(const ushort4*)(oht + (size_t)plane * NHW + (w0 + r) * NP + h0 + c4);
    ts[r][c4 + 0] = v.x; ts[r][c4 + 1] = v.y; ts[r][c4 + 2] = v.z; ts[r][c4 + 3] = v.w;
    __syncthreads();
    float* dst = out + (size_t)plane * NHW + (h0 + r) * NP + w0 + c4;
    float4 cur = *(const float4*)dst;
    cur.x += h2f(ts[c4 + 0][r]);
    cur.y += h2f(ts[c4 + 1][r]);
    cur.z += h2f(ts[c4 + 2][r]);
    cur.w += h2f(ts[c4 + 3][r]);
    *(float4*)dst = cur;
}

extern "C" void kernel_launch(void* const* d_in, const int* in_sizes, int n_in,
                              void* d_out, int out_size, void* d_ws, size_t ws_size,
                              hipStream_t stream) {
    const float* x  = (const float*)d_in[0];
    const float* wq = (const float*)d_in[1];
    const float* bq = (const float*)d_in[2];
    const float* wk = (const float*)d_in[3];
    const float* bk = (const float*)d_in[4];
    float* out = (float*)d_out;

    const size_t QKE = (size_t)NB * NHW * NK;  // 16,777,216 elems
    const size_t XE  = (size_t)NB * NC * NHW;  // 67,108,864 elems
    const size_t WHE = (size_t)256 * 512;
    u16* wh  = (u16*)d_ws;
    u16* q   = wh + WHE;
    u16* k   = q + QKE;
    u16* xt  = k + QKE;
    u16* oht = xt + XE;
    u16* owh = oht + XE;
    const size_t need_big = (WHE + 2 * QKE + 3 * XE) * sizeof(u16);  // ~470 MiB
    const bool big = ws_size >= need_big;

    dim3 blk(256);
    dim3 ablk(512);

    // 0. weights -> fp16
    wconv_kernel<<<dim3(256), blk, 0, stream>>>(wq, wk, wh);
    // 1. x -> xt fp16 transposed [b][c][w][h]
    convtr_kernel<<<dim3(16, NB * NC), blk, 0, stream>>>(x, xt);
    // 2. fused q,k projection (MFMA v3), pixel-major fp16
    proj_kernel<<<dim3(NHW / 64, NB), blk, 0, stream>>>(x, wh, bq, bk, q, k);

    if (big) {
        // 3. merged W+H attention, 512 threads, K-in-LDS, PV c-tile 128
        attn_kernel<1><<<dim3(NP, NB, 2), ablk, 0, stream>>>(q, k, x, xt, owh, oht, out);
        // 4. out = owh + oht^T
        combine_kernel<<<dim3(16, NB * NC), blk, 0, stream>>>(owh, oht, out);
    } else {
        // fallback: W-pass writes out fp32 directly, then RMW-add of oht^T
        attn_kernel<0><<<dim3(NP, NB, 2), ablk, 0, stream>>>(q, k, x, xt, owh, oht, out);
        addtr_kernel<<<dim3(16, NB * NC), blk, 0, stream>>>(oht, out);
    }
}

// Round 19
// 454.598 us; speedup vs baseline: 1.0253x; 1.0253x over previous
//
#include <hip/hip_runtime.h>
#include <hip/hip_fp16.h>

#define NB 8
#define NC 512
#define NK 128   // key_dim C2
#define NP 128   // positions per attention row (H = W = 128)
#define NHW 16384

typedef unsigned short u16;
typedef unsigned int u32;
typedef float f32x4 __attribute__((ext_vector_type(4)));
typedef _Float16 f16x8 __attribute__((ext_vector_type(8)));

__device__ __forceinline__ u16 f2h(float f) { return __half_as_ushort(__float2half(f)); }
__device__ __forceinline__ float h2f(u16 u) { return __half2float(__ushort_as_half(u)); }

// ---------------- weights fp32 -> fp16, concatenated [wq;wk] row-major ----------------
__global__ __launch_bounds__(256) void wconv_kernel(const float* __restrict__ wq,
                                                    const float* __restrict__ wk,
                                                    u16* __restrict__ wh) {
    int row = blockIdx.x;  // 0..255
    const float* src = (row < 128) ? (wq + (size_t)row * NC) : (wk + (size_t)(row - 128) * NC);
    int t = threadIdx.x;
    float2 v = *(const float2*)(src + t * 2);
    ushort2 o; o.x = f2h(v.x); o.y = f2h(v.y);
    *(ushort2*)(wh + (size_t)row * NC + t * 2) = o;
}

// ---------------- x fp32 [plane][h][w] -> xt fp16 [plane][w][h] ----------------
__global__ __launch_bounds__(256) void convtr_kernel(const float* __restrict__ x,
                                                     u16* __restrict__ xt) {
    __shared__ u16 ts[32][36];
    int plane = blockIdx.y;
    int tile  = blockIdx.x;
    int h0 = (tile >> 2) * 32, w0 = (tile & 3) * 32;
    const float* ip = x + (size_t)plane * NHW;
    u16* op = xt + (size_t)plane * NHW;
    int r  = threadIdx.x >> 3;
    int c4 = (threadIdx.x & 7) * 4;
    float4 v = *(const float4*)(ip + (h0 + r) * NP + w0 + c4);
    ts[r][c4 + 0] = f2h(v.x); ts[r][c4 + 1] = f2h(v.y);
    ts[r][c4 + 2] = f2h(v.z); ts[r][c4 + 3] = f2h(v.w);
    __syncthreads();
    ushort4 o;
    o.x = ts[c4 + 0][r]; o.y = ts[c4 + 1][r]; o.z = ts[c4 + 2][r]; o.w = ts[c4 + 3][r];
    *(ushort4*)(op + (w0 + r) * NP + h0 + c4) = o;
}

// ---------------- fused q+k projection via MFMA (v3, unchanged) ----------------
#define XROW 40   // u16 stride of one p-row (80 B, 16B-aligned)
__device__ __forceinline__ int xt2_off(int p, int cw) {
    int sw = ((p >> 3) & 3) << 2;
    return p * XROW + 2 * (cw ^ sw);
}

__global__ __launch_bounds__(256, 3) void proj_kernel(const float* __restrict__ x,
                                                      const u16* __restrict__ wh,
                                                      const float* __restrict__ bq,
                                                      const float* __restrict__ bk,
                                                      u16* __restrict__ q,
                                                      u16* __restrict__ k) {
    __shared__ __align__(16) u16 smem[9216];
    int b  = blockIdx.y;
    int p0 = blockIdx.x * 64;
    int tid = threadIdx.x;
    int lane = tid & 63, w = tid >> 6;
    int ln = lane & 15, g = lane >> 4;

    float biasv[4];
#pragma unroll
    for (int nf = 0; nf < 4; nf++) {
        int oc = w * 64 + nf * 16 + ln;
        biasv[nf] = (oc < 128) ? bq[oc] : bk[oc - 128];
    }

    f32x4 acc[4][4];
#pragma unroll
    for (int mf = 0; mf < 4; mf++)
#pragma unroll
        for (int nf = 0; nf < 4; nf++) acc[mf][nf] = 0.0f;

    int si  = tid >> 4;          // 0..15
    int spx = (tid & 15) * 4;

#define STAGE(buf, c0)                                                                  \
    {                                                                                   \
        const float* xa = x + ((size_t)(b * NC + (c0) + 2 * si)) * NHW + p0 + spx;      \
        const float* xb = xa + NHW;                                                     \
        float4 a0 = *(const float4*)xa;                                                 \
        float4 b0 = *(const float4*)xb;                                                 \
        float av[4] = {a0.x, a0.y, a0.z, a0.w};                                         \
        float bv[4] = {b0.x, b0.y, b0.z, b0.w};                                         \
        _Pragma("unroll") for (int j = 0; j < 4; j++) {                                 \
            ushort2 pk;                                                                 \
            pk.x = f2h(av[j]); pk.y = f2h(bv[j]);                                       \
            *(ushort2*)&smem[(buf) * 2560 + xt2_off(spx + j, si)] = pk;                 \
        }                                                                               \
    }

    STAGE(0, 0);
    __syncthreads();
    for (int t = 0; t < 16; ++t) {
        int c0 = t * 32;
        if (t < 15) STAGE((t + 1) & 1, c0 + 32);
        f16x8 bf[4];
#pragma unroll
        for (int nf = 0; nf < 4; nf++)
            bf[nf] = *(const f16x8*)&wh[((size_t)(w * 64 + nf * 16 + ln)) * NC + c0 + g * 8];
        f16x8 af[4];
#pragma unroll
        for (int mf = 0; mf < 4; mf++)
            af[mf] = *(const f16x8*)&smem[(t & 1) * 2560 + xt2_off(mf * 16 + ln, g * 4)];
#pragma unroll
        for (int mf = 0; mf < 4; mf++)
#pragma unroll
            for (int nf = 0; nf < 4; nf++)
                acc[mf][nf] = __builtin_amdgcn_mfma_f32_16x16x32_f16(af[mf], bf[nf], acc[mf][nf], 0, 0, 0);
        __syncthreads();
    }
#undef STAGE

#pragma unroll
    for (int pass = 0; pass < 2; pass++) {
        if ((w >> 1) == pass) {
            int colbase = (w & 1) * 64;
#pragma unroll
            for (int mf = 0; mf < 4; mf++)
#pragma unroll
                for (int nf = 0; nf < 4; nf++)
#pragma unroll
                    for (int rg = 0; rg < 4; rg++) {
                        int p = mf * 16 + g * 4 + rg;
                        smem[p * 136 + colbase + nf * 16 + ln] = f2h(acc[mf][nf][rg] + biasv[nf]);
                    }
        }
        __syncthreads();
        {
            int p = tid >> 2, seg = tid & 3;
            u16* dst = (pass == 0 ? q : k) + ((size_t)(b * NHW + p0 + p)) * NK + seg * 32;
            const u16* srcl = &smem[p * 136 + seg * 32];
            *(uint4*)(dst)     = *(const uint4*)(srcl);
            *(uint4*)(dst + 8) = *(const uint4*)(srcl + 8);
            *(uint4*)(dst + 16) = *(const uint4*)(srcl + 16);
            *(uint4*)(dst + 24) = *(const uint4*)(srcl + 24);
        }
        __syncthreads();
    }
}

// ---------------- merged axis attention via MFMA — 512 threads / 8 waves (champion, r16 bench) ----------------
// zp=0: W-pass — r=h, Q/K rows contiguous, V = x fp32 (cvt), out = owh fp16 (WOH=1) or outw fp32
// zp=1: H-pass — r=w, Q/K rows strided,   V = xt fp16,       out = oht fp16
// E: wave (wj=w>>2, wi=w&3) owns 64j x 32i -> e[4][2]. PV: wave (wc=w>>2, wi2=w&3) owns 32c x 32i.
template <int WOH>
__global__ __launch_bounds__(512) void attn_kernel(const u16* __restrict__ q,
                                                   const u16* __restrict__ k,
                                                   const float* __restrict__ x,
                                                   const u16* __restrict__ xt,
                                                   u16* __restrict__ owh,
                                                   u16* __restrict__ oht,
                                                   float* __restrict__ outw) {
    __shared__ __align__(16) u16 smem[2 * 128 * 136];
    __shared__ float redmax[256];
    __shared__ float redsum[256];
    u16* Ks = smem;
    u16* Qs = smem + 128 * 136;
    u16* Al = smem;
    u16* Vl = smem + 128 * 136;

    int r = blockIdx.x, b = blockIdx.y;
    int zp = blockIdx.z;   // 0 = W-pass, 1 = H-pass
    int tid = threadIdx.x;
    int lane = tid & 63, w = tid >> 6;
    int ln = lane & 15, g = lane >> 4;

    const size_t base = zp ? ((size_t)b * NHW + r) * NK : ((size_t)b * NHW + (size_t)r * NP) * NK;
    const int qrs = zp ? NP * NK : NK;

    // stage Q,K position-major [j][c]: 512 threads, 64B per matrix each
    {
        int j = tid >> 2, hf = tid & 3;
        const u16* qp2 = q + base + (size_t)j * qrs + hf * 32;
        const u16* kp2 = k + base + (size_t)j * qrs + hf * 32;
#pragma unroll
        for (int e = 0; e < 4; e++) {
            *(uint4*)&Qs[j * 136 + hf * 32 + e * 8] = *(const uint4*)(qp2 + e * 8);
            *(uint4*)&Ks[j * 136 + hf * 32 + e * 8] = *(const uint4*)(kp2 + e * 8);
        }
    }
    __syncthreads();

    // ---- E^T: wave (wj, wi), tile 64j x 32i ----
    int wj = w >> 2, wi = w & 3;
    f32x4 e[4][2];
#pragma unroll
    for (int mf = 0; mf < 4; mf++)
#pragma unroll
        for (int nf = 0; nf < 2; nf++) e[mf][nf] = 0.0f;
#pragma unroll
    for (int ks = 0; ks < 4; ks++) {
        f16x8 qa[4], kb[2];
#pragma unroll
        for (int mf = 0; mf < 4; mf++)
            qa[mf] = *(const f16x8*)&Qs[(wj * 64 + mf * 16 + ln) * 136 + ks * 32 + g * 8];
#pragma unroll
        for (int nf = 0; nf < 2; nf++)
            kb[nf] = *(const f16x8*)&Ks[(wi * 32 + nf * 16 + ln) * 136 + ks * 32 + g * 8];
#pragma unroll
        for (int mf = 0; mf < 4; mf++)
#pragma unroll
            for (int nf = 0; nf < 2; nf++)
                e[mf][nf] = __builtin_amdgcn_mfma_f32_16x16x32_f16(qa[mf], kb[nf], e[mf][nf], 0, 0, 0);
    }

    // ---- softmax over j; lane's i columns: i = wi*32 + nf*16 + ln ----
    float pm[2];
#pragma unroll
    for (int nf = 0; nf < 2; nf++) {
        pm[nf] = -3.0e38f;
#pragma unroll
        for (int mf = 0; mf < 4; mf++)
#pragma unroll
            for (int rg = 0; rg < 4; rg++) pm[nf] = fmaxf(pm[nf], e[mf][nf][rg]);
        pm[nf] = fmaxf(pm[nf], __shfl_xor(pm[nf], 16));
        pm[nf] = fmaxf(pm[nf], __shfl_xor(pm[nf], 32));
    }
    if (g == 0) {
#pragma unroll
        for (int nf = 0; nf < 2; nf++) redmax[wj * 128 + wi * 32 + nf * 16 + ln] = pm[nf];
    }
    __syncthreads();
    float fm[2];
#pragma unroll
    for (int nf = 0; nf < 2; nf++) {
        int i = wi * 32 + nf * 16 + ln;
        fm[nf] = fmaxf(redmax[i], redmax[128 + i]);
    }
    float ps[2] = {0.f, 0.f};
#pragma unroll
    for (int mf = 0; mf < 4; mf++)
#pragma unroll
        for (int nf = 0; nf < 2; nf++)
#pragma unroll
            for (int rg = 0; rg < 4; rg++) {
                float v = __expf(e[mf][nf][rg] - fm[nf]);
                e[mf][nf][rg] = v;
                ps[nf] += v;
            }
#pragma unroll
    for (int nf = 0; nf < 2; nf++) {
        ps[nf] += __shfl_xor(ps[nf], 16);
        ps[nf] += __shfl_xor(ps[nf], 32);
    }
    if (g == 0) {
#pragma unroll
        for (int nf = 0; nf < 2; nf++) redsum[wj * 128 + wi * 32 + nf * 16 + ln] = ps[nf];
    }
    __syncthreads();
    float ivs[2];
#pragma unroll
    for (int nf = 0; nf < 2; nf++) {
        int i = wi * 32 + nf * 16 + ln;
        ivs[nf] = 1.0f / (redsum[i] + redsum[128 + i]);
    }
    // pack A fp16 into Al[i][j] (region A = Qs; all cross-wave Qs reads completed before the
    // redmax __syncthreads above, so overwriting is safe)
#pragma unroll
    for (int mf = 0; mf < 4; mf++)
#pragma unroll
        for (int nf = 0; nf < 2; nf++) {
            ushort4 pk;
            pk.x = f2h(e[mf][nf][0] * ivs[nf]);
            pk.y = f2h(e[mf][nf][1] * ivs[nf]);
            pk.z = f2h(e[mf][nf][2] * ivs[nf]);
            pk.w = f2h(e[mf][nf][3] * ivs[nf]);
            *(ushort4*)&Al[(wi * 32 + nf * 16 + ln) * 136 + wj * 64 + mf * 16 + g * 4] = pk;
        }
    __syncthreads();

    // ---- PV: wave (wc, wi2) owns 32c x 32i per c-tile of 64 ----
    int wc = w >> 2, wi2 = w & 3;
    f16x8 bfr[2][4];
#pragma unroll
    for (int nf2 = 0; nf2 < 2; nf2++)
#pragma unroll
        for (int js = 0; js < 4; js++)
            bfr[nf2][js] = *(const f16x8*)&Al[(wi2 * 32 + nf2 * 16 + ln) * 136 + js * 32 + g * 8];

    int cc = tid >> 3, ch = (tid & 7) * 16;   // 64 rows x 128 cols, 16 u16/thread
    u16 vh[16];
#define LOADV(c0)                                                                           \
    {                                                                                       \
        if (zp) {                                                                           \
            const u16* vn = xt + ((size_t)(b * NC + (c0) + cc)) * NHW + (size_t)r * NP + ch;\
            *(uint4*)&vh[0] = *(const uint4*)(vn);                                          \
            *(uint4*)&vh[8] = *(const uint4*)(vn + 8);                                      \
        } else {                                                                            \
            const float* vn = x + ((size_t)(b * NC + (c0) + cc)) * NHW + (size_t)r * NP + ch;\
            _Pragma("unroll") for (int e2 = 0; e2 < 4; e2++) {                              \
                float4 vv = *(const float4*)(vn + e2 * 4);                                  \
                vh[e2 * 4 + 0] = f2h(vv.x); vh[e2 * 4 + 1] = f2h(vv.y);                     \
                vh[e2 * 4 + 2] = f2h(vv.z); vh[e2 * 4 + 3] = f2h(vv.w);                     \
            }                                                                               \
        }                                                                                   \
    }

    LOADV(0);
    for (int c0 = 0; c0 < NC; c0 += 64) {
        *(uint4*)&Vl[cc * 136 + ch] = *(uint4*)&vh[0];
        *(uint4*)&Vl[cc * 136 + ch + 8] = *(uint4*)&vh[8];
        __syncthreads();
        if (c0 + 64 < NC) LOADV(c0 + 64);   // hide next tile's HBM latency under MFMA
        f32x4 o[2][2];
#pragma unroll
        for (int mf2 = 0; mf2 < 2; mf2++)
#pragma unroll
            for (int nf2 = 0; nf2 < 2; nf2++) o[mf2][nf2] = 0.0f;
#pragma unroll
        for (int js = 0; js < 4; js++) {
            f16x8 va[2];
#pragma unroll
            for (int mf2 = 0; mf2 < 2; mf2++)
                va[mf2] = *(const f16x8*)&Vl[(wc * 32 + mf2 * 16 + ln) * 136 + js * 32 + g * 8];
#pragma unroll
            for (int mf2 = 0; mf2 < 2; mf2++)
#pragma unroll
                for (int nf2 = 0; nf2 < 2; nf2++)
                    o[mf2][nf2] = __builtin_amdgcn_mfma_f32_16x16x32_f16(va[mf2], bfr[nf2][js], o[mf2][nf2], 0, 0, 0);
        }
#pragma unroll
        for (int mf2 = 0; mf2 < 2; mf2++)
#pragma unroll
            for (int nf2 = 0; nf2 < 2; nf2++)
#pragma unroll
                for (int rg = 0; rg < 4; rg++) {
                    int ci = c0 + wc * 32 + mf2 * 16 + g * 4 + rg;
                    int ii = wi2 * 32 + nf2 * 16 + ln;
                    size_t oa = ((size_t)(b * NC + ci)) * NHW + (size_t)r * NP + ii;
                    if (zp)           oht[oa] = f2h(o[mf2][nf2][rg]);
                    else if (WOH)     owh[oa] = f2h(o[mf2][nf2][rg]);
                    else              outw[oa] = o[mf2][nf2][rg];
                }
        __syncthreads();
    }
#undef LOADV
}

// ---------------- out[plane][h][w] = owh[plane][h][w] + oht[plane][w][h] ----------------
__global__ __launch_bounds__(256) void combine_kernel(const u16* __restrict__ owh,
                                                      const u16* __restrict__ oht,
                                                      float* __restrict__ out) {
    __shared__ u16 ts[32][36];
    int plane = blockIdx.y;
    int tile  = blockIdx.x;
    int h0 = (tile >> 2) * 32, w0 = (tile & 3) * 32;
    int r  = threadIdx.x >> 3;
    int c4 = (threadIdx.x & 7) * 4;
    ushort4 v = *(const ushort4*)(oht + (size_t)plane * NHW + (w0 + r) * NP + h0 + c4);
    ts[r][c4 + 0] = v.x; ts[r][c4 + 1] = v.y; ts[r][c4 + 2] = v.z; ts[r][c4 + 3] = v.w;
    __syncthreads();
    ushort4 a = *(const ushort4*)(owh + (size_t)plane * NHW + (h0 + r) * NP + w0 + c4);
    float4 o;
    o.x = h2f(a.x) + h2f(ts[c4 + 0][r]);
    o.y = h2f(a.y) + h2f(ts[c4 + 1][r]);
    o.z = h2f(a.z) + h2f(ts[c4 + 2][r]);
    o.w = h2f(a.w) + h2f(ts[c4 + 3][r]);
    *(float4*)(out + (size_t)plane * NHW + (h0 + r) * NP + w0 + c4) = o;
}

// ---------------- fallback: out[plane][h][w] += oht[plane][w][h] (fp16 -> fp32 RMW) ----------------
__global__ __launch_bounds__(256) void addtr_kernel(const u16* __restrict__ oht,
                                                    float* __restrict__ out) {
    __shared__ u16 ts[32][36];
    int plane = blockIdx.y;
    int tile  = blockIdx.x;
    int h0 = (tile >> 2) * 32, w0 = (tile & 3) * 32;
    int r  = threadIdx.x >> 3;
    int c4 = (threadIdx.x & 7) * 4;
    ushort4 v = *(const ushort4*)(oht + (size_t)plane * NHW + (w0 + r) * NP + h0 + c4);
    ts[r][c4 + 0] = v.x; ts[r][c4 + 1] = v.y; ts[r][c4 + 2] = v.z; ts[r][c4 + 3] = v.w;
    __syncthreads();
    float* dst = out + (size_t)plane * NHW + (h0 + r) * NP + w0 + c4;
    float4 cur = *(const float4*)dst;
    cur.x += h2f(ts[c4 + 0][r]);
    cur.y += h2f(ts[c4 + 1][r]);
    cur.z += h2f(ts[c4 + 2][r]);
    cur.w += h2f(ts[c4 + 3][r]);
    *(float4*)dst = cur;
}

extern "C" void kernel_launch(void* const* d_in, const int* in_sizes, int n_in,
                              void* d_out, int out_size, void* d_ws, size_t ws_size,
                              hipStream_t stream) {
    const float* x  = (const float*)d_in[0];
    const float* wq = (const float*)d_in[1];
    const float* bq = (const float*)d_in[2];
    const float* wk = (const float*)d_in[3];
    const float* bk = (const float*)d_in[4];
    float* out = (float*)d_out;

    const size_t QKE = (size_t)NB * NHW * NK;  // 16,777,216 elems
    const size_t XE  = (size_t)NB * NC * NHW;  // 67,108,864 elems
    const size_t WHE = (size_t)256 * 512;
    u16* wh  = (u16*)d_ws;
    u16* q   = wh + WHE;
    u16* k   = q + QKE;
    u16* xt  = k + QKE;
    u16* oht = xt + XE;
    u16* owh = oht + XE;
    const size_t need_big = (WHE + 2 * QKE + 3 * XE) * sizeof(u16);  // ~470 MiB
    const bool big = ws_size >= need_big;

    dim3 blk(256);
    dim3 ablk(512);

    // 0. weights -> fp16
    wconv_kernel<<<dim3(256), blk, 0, stream>>>(wq, wk, wh);
    // 1. x -> xt fp16 transposed [b][c][w][h]
    convtr_kernel<<<dim3(16, NB * NC), blk, 0, stream>>>(x, xt);
    // 2. fused q,k projection (MFMA v3), pixel-major fp16
    proj_kernel<<<dim3(NHW / 64, NB), blk, 0, stream>>>(x, wh, bq, bk, q, k);

    if (big) {
        // 3. merged W+H attention, 512 threads (z=0: W->owh fp16, z=1: H->oht fp16)
        attn_kernel<1><<<dim3(NP, NB, 2), ablk, 0, stream>>>(q, k, x, xt, owh, oht, out);
        // 4. out = owh + oht^T
        combine_kernel<<<dim3(16, NB * NC), blk, 0, stream>>>(owh, oht, out);
    } else {
        // fallback: W-pass writes out fp32 directly, then RMW-add of oht^T
        attn_kernel<0><<<dim3(NP, NB, 2), ablk, 0, stream>>>(q, k, x, xt, owh, oht, out);
        addtr_kernel<<<dim3(16, NB * NC), blk, 0, stream>>>(oht, out);
    }
}

// Round 20
// 451.499 us; speedup vs baseline: 1.0323x; 1.0069x over previous
//
#include <hip/hip_runtime.h>
#include <hip/hip_fp16.h>

#define NB 8
#define NC 512
#define NK 128   // key_dim C2
#define NP 128   // positions per attention row (H = W = 128)
#define NHW 16384

typedef unsigned short u16;
typedef unsigned int u32;
typedef float f32x4 __attribute__((ext_vector_type(4)));
typedef _Float16 f16x8 __attribute__((ext_vector_type(8)));

__device__ __forceinline__ u16 f2h(float f) { return __half_as_ushort(__float2half(f)); }
__device__ __forceinline__ float h2f(u16 u) { return __half2float(__ushort_as_half(u)); }

// ---------------- weights fp32 -> fp16, concatenated [wq;wk] row-major ----------------
__global__ __launch_bounds__(256) void wconv_kernel(const float* __restrict__ wq,
                                                    const float* __restrict__ wk,
                                                    u16* __restrict__ wh) {
    int row = blockIdx.x;  // 0..255
    const float* src = (row < 128) ? (wq + (size_t)row * NC) : (wk + (size_t)(row - 128) * NC);
    int t = threadIdx.x;
    float2 v = *(const float2*)(src + t * 2);
    ushort2 o; o.x = f2h(v.x); o.y = f2h(v.y);
    *(ushort2*)(wh + (size_t)row * NC + t * 2) = o;
}

// ---------------- x fp32 [plane][h][w] -> xt fp16 [plane][w][h] ----------------
__global__ __launch_bounds__(256) void convtr_kernel(const float* __restrict__ x,
                                                     u16* __restrict__ xt) {
    __shared__ u16 ts[32][36];
    int plane = blockIdx.y;
    int tile  = blockIdx.x;
    int h0 = (tile >> 2) * 32, w0 = (tile & 3) * 32;
    const float* ip = x + (size_t)plane * NHW;
    u16* op = xt + (size_t)plane * NHW;
    int r  = threadIdx.x >> 3;
    int c4 = (threadIdx.x & 7) * 4;
    float4 v = *(const float4*)(ip + (h0 + r) * NP + w0 + c4);
    ts[r][c4 + 0] = f2h(v.x); ts[r][c4 + 1] = f2h(v.y);
    ts[r][c4 + 2] = f2h(v.z); ts[r][c4 + 3] = f2h(v.w);
    __syncthreads();
    ushort4 o;
    o.x = ts[c4 + 0][r]; o.y = ts[c4 + 1][r]; o.z = ts[c4 + 2][r]; o.w = ts[c4 + 3][r];
    *(ushort4*)(op + (w0 + r) * NP + h0 + c4) = o;
}

// ---------------- fused q+k projection via MFMA (v3, unchanged) ----------------
#define XROW 40   // u16 stride of one p-row (80 B, 16B-aligned)
__device__ __forceinline__ int xt2_off(int p, int cw) {
    int sw = ((p >> 3) & 3) << 2;
    return p * XROW + 2 * (cw ^ sw);
}

__global__ __launch_bounds__(256, 3) void proj_kernel(const float* __restrict__ x,
                                                      const u16* __restrict__ wh,
                                                      const float* __restrict__ bq,
                                                      const float* __restrict__ bk,
                                                      u16* __restrict__ q,
                                                      u16* __restrict__ k) {
    __shared__ __align__(16) u16 smem[9216];
    int b  = blockIdx.y;
    int p0 = blockIdx.x * 64;
    int tid = threadIdx.x;
    int lane = tid & 63, w = tid >> 6;
    int ln = lane & 15, g = lane >> 4;

    float biasv[4];
#pragma unroll
    for (int nf = 0; nf < 4; nf++) {
        int oc = w * 64 + nf * 16 + ln;
        biasv[nf] = (oc < 128) ? bq[oc] : bk[oc - 128];
    }

    f32x4 acc[4][4];
#pragma unroll
    for (int mf = 0; mf < 4; mf++)
#pragma unroll
        for (int nf = 0; nf < 4; nf++) acc[mf][nf] = 0.0f;

    int si  = tid >> 4;          // 0..15
    int spx = (tid & 15) * 4;

#define STAGE(buf, c0)                                                                  \
    {                                                                                   \
        const float* xa = x + ((size_t)(b * NC + (c0) + 2 * si)) * NHW + p0 + spx;      \
        const float* xb = xa + NHW;                                                     \
        float4 a0 = *(const float4*)xa;                                                 \
        float4 b0 = *(const float4*)xb;                                                 \
        float av[4] = {a0.x, a0.y, a0.z, a0.w};                                         \
        float bv[4] = {b0.x, b0.y, b0.z, b0.w};                                         \
        _Pragma("unroll") for (int j = 0; j < 4; j++) {                                 \
            ushort2 pk;                                                                 \
            pk.x = f2h(av[j]); pk.y = f2h(bv[j]);                                       \
            *(ushort2*)&smem[(buf) * 2560 + xt2_off(spx + j, si)] = pk;                 \
        }                                                                               \
    }

    STAGE(0, 0);
    __syncthreads();
    for (int t = 0; t < 16; ++t) {
        int c0 = t * 32;
        if (t < 15) STAGE((t + 1) & 1, c0 + 32);
        f16x8 bf[4];
#pragma unroll
        for (int nf = 0; nf < 4; nf++)
            bf[nf] = *(const f16x8*)&wh[((size_t)(w * 64 + nf * 16 + ln)) * NC + c0 + g * 8];
        f16x8 af[4];
#pragma unroll
        for (int mf = 0; mf < 4; mf++)
            af[mf] = *(const f16x8*)&smem[(t & 1) * 2560 + xt2_off(mf * 16 + ln, g * 4)];
#pragma unroll
        for (int mf = 0; mf < 4; mf++)
#pragma unroll
            for (int nf = 0; nf < 4; nf++)
                acc[mf][nf] = __builtin_amdgcn_mfma_f32_16x16x32_f16(af[mf], bf[nf], acc[mf][nf], 0, 0, 0);
        __syncthreads();
    }
#undef STAGE

#pragma unroll
    for (int pass = 0; pass < 2; pass++) {
        if ((w >> 1) == pass) {
            int colbase = (w & 1) * 64;
#pragma unroll
            for (int mf = 0; mf < 4; mf++)
#pragma unroll
                for (int nf = 0; nf < 4; nf++)
#pragma unroll
                    for (int rg = 0; rg < 4; rg++) {
                        int p = mf * 16 + g * 4 + rg;
                        smem[p * 136 + colbase + nf * 16 + ln] = f2h(acc[mf][nf][rg] + biasv[nf]);
                    }
        }
        __syncthreads();
        {
            int p = tid >> 2, seg = tid & 3;
            u16* dst = (pass == 0 ? q : k) + ((size_t)(b * NHW + p0 + p)) * NK + seg * 32;
            const u16* srcl = &smem[p * 136 + seg * 32];
            *(uint4*)(dst)     = *(const uint4*)(srcl);
            *(uint4*)(dst + 8) = *(const uint4*)(srcl + 8);
            *(uint4*)(dst + 16) = *(const uint4*)(srcl + 16);
            *(uint4*)(dst + 24) = *(const uint4*)(srcl + 24);
        }
        __syncthreads();
    }
}

// ---------------- merged axis attention via MFMA — 512 threads, coalesced O stores ----------------
// zp=0: W-pass — r=h, Q/K rows contiguous, V = x fp32 (cvt), out = owh fp16 (WOH=1) or outw fp32
// zp=1: H-pass — r=w, Q/K rows strided,   V = xt fp16,       out = oht fp16
// E: wave (wj=w>>2, wi=w&3) owns 64j x 32i -> e[4][2]. PV: wave (wc=w>>2, wi2=w&3) owns 32c x 32i.
// PV output is bounced through the dead Al region (bfr hoisted to regs) for uint4 stores.
template <int WOH>
__global__ __launch_bounds__(512) void attn_kernel(const u16* __restrict__ q,
                                                   const u16* __restrict__ k,
                                                   const float* __restrict__ x,
                                                   const u16* __restrict__ xt,
                                                   u16* __restrict__ owh,
                                                   u16* __restrict__ oht,
                                                   float* __restrict__ outw) {
    __shared__ __align__(16) u16 smem[2 * 128 * 136];
    __shared__ float redmax[256];
    __shared__ float redsum[256];
    u16* Ks = smem;
    u16* Qs = smem + 128 * 136;
    u16* Al = smem;
    u16* Vl = smem + 128 * 136;
    u16* Ob = smem;              // PV output bounce: overlays Al (dead after bfr hoist)

    int r = blockIdx.x, b = blockIdx.y;
    int zp = blockIdx.z;   // 0 = W-pass, 1 = H-pass
    int tid = threadIdx.x;
    int lane = tid & 63, w = tid >> 6;
    int ln = lane & 15, g = lane >> 4;

    const size_t base = zp ? ((size_t)b * NHW + r) * NK : ((size_t)b * NHW + (size_t)r * NP) * NK;
    const int qrs = zp ? NP * NK : NK;

    // stage Q,K position-major [j][c]: 512 threads, 64B per matrix each
    {
        int j = tid >> 2, hf = tid & 3;
        const u16* qp2 = q + base + (size_t)j * qrs + hf * 32;
        const u16* kp2 = k + base + (size_t)j * qrs + hf * 32;
#pragma unroll
        for (int e = 0; e < 4; e++) {
            *(uint4*)&Qs[j * 136 + hf * 32 + e * 8] = *(const uint4*)(qp2 + e * 8);
            *(uint4*)&Ks[j * 136 + hf * 32 + e * 8] = *(const uint4*)(kp2 + e * 8);
        }
    }
    __syncthreads();

    // ---- E^T: wave (wj, wi), tile 64j x 32i ----
    int wj = w >> 2, wi = w & 3;
    f32x4 e[4][2];
#pragma unroll
    for (int mf = 0; mf < 4; mf++)
#pragma unroll
        for (int nf = 0; nf < 2; nf++) e[mf][nf] = 0.0f;
#pragma unroll
    for (int ks = 0; ks < 4; ks++) {
        f16x8 qa[4], kb[2];
#pragma unroll
        for (int mf = 0; mf < 4; mf++)
            qa[mf] = *(const f16x8*)&Qs[(wj * 64 + mf * 16 + ln) * 136 + ks * 32 + g * 8];
#pragma unroll
        for (int nf = 0; nf < 2; nf++)
            kb[nf] = *(const f16x8*)&Ks[(wi * 32 + nf * 16 + ln) * 136 + ks * 32 + g * 8];
#pragma unroll
        for (int mf = 0; mf < 4; mf++)
#pragma unroll
            for (int nf = 0; nf < 2; nf++)
                e[mf][nf] = __builtin_amdgcn_mfma_f32_16x16x32_f16(qa[mf], kb[nf], e[mf][nf], 0, 0, 0);
    }

    // ---- softmax over j; lane's i columns: i = wi*32 + nf*16 + ln ----
    float pm[2];
#pragma unroll
    for (int nf = 0; nf < 2; nf++) {
        pm[nf] = -3.0e38f;
#pragma unroll
        for (int mf = 0; mf < 4; mf++)
#pragma unroll
            for (int rg = 0; rg < 4; rg++) pm[nf] = fmaxf(pm[nf], e[mf][nf][rg]);
        pm[nf] = fmaxf(pm[nf], __shfl_xor(pm[nf], 16));
        pm[nf] = fmaxf(pm[nf], __shfl_xor(pm[nf], 32));
    }
    if (g == 0) {
#pragma unroll
        for (int nf = 0; nf < 2; nf++) redmax[wj * 128 + wi * 32 + nf * 16 + ln] = pm[nf];
    }
    __syncthreads();
    float fm[2];
#pragma unroll
    for (int nf = 0; nf < 2; nf++) {
        int i = wi * 32 + nf * 16 + ln;
        fm[nf] = fmaxf(redmax[i], redmax[128 + i]);
    }
    float ps[2] = {0.f, 0.f};
#pragma unroll
    for (int mf = 0; mf < 4; mf++)
#pragma unroll
        for (int nf = 0; nf < 2; nf++)
#pragma unroll
            for (int rg = 0; rg < 4; rg++) {
                float v = __expf(e[mf][nf][rg] - fm[nf]);
                e[mf][nf][rg] = v;
                ps[nf] += v;
            }
#pragma unroll
    for (int nf = 0; nf < 2; nf++) {
        ps[nf] += __shfl_xor(ps[nf], 16);
        ps[nf] += __shfl_xor(ps[nf], 32);
    }
    if (g == 0) {
#pragma unroll
        for (int nf = 0; nf < 2; nf++) redsum[wj * 128 + wi * 32 + nf * 16 + ln] = ps[nf];
    }
    __syncthreads();
    float ivs[2];
#pragma unroll
    for (int nf = 0; nf < 2; nf++) {
        int i = wi * 32 + nf * 16 + ln;
        ivs[nf] = 1.0f / (redsum[i] + redsum[128 + i]);
    }
    // pack A fp16 into Al[i][j] (region A = Qs; all cross-wave Qs reads completed before the
    // redmax __syncthreads above, so overwriting is safe)
#pragma unroll
    for (int mf = 0; mf < 4; mf++)
#pragma unroll
        for (int nf = 0; nf < 2; nf++) {
            ushort4 pk;
            pk.x = f2h(e[mf][nf][0] * ivs[nf]);
            pk.y = f2h(e[mf][nf][1] * ivs[nf]);
            pk.z = f2h(e[mf][nf][2] * ivs[nf]);
            pk.w = f2h(e[mf][nf][3] * ivs[nf]);
            *(ushort4*)&Al[(wi * 32 + nf * 16 + ln) * 136 + wj * 64 + mf * 16 + g * 4] = pk;
        }
    __syncthreads();

    // ---- PV: wave (wc, wi2) owns 32c x 32i per c-tile of 64 ----
    int wc = w >> 2, wi2 = w & 3;
    f16x8 bfr[2][4];
#pragma unroll
    for (int nf2 = 0; nf2 < 2; nf2++)
#pragma unroll
        for (int js = 0; js < 4; js++)
            bfr[nf2][js] = *(const f16x8*)&Al[(wi2 * 32 + nf2 * 16 + ln) * 136 + js * 32 + g * 8];
    __syncthreads();   // all bfr reads of Al done -> region A free for Ob

    int cc = tid >> 3, ch = (tid & 7) * 16;   // 64 rows x 128 cols, 16 u16/thread
    u16 vh[16];
#define LOADV(c0)                                                                           \
    {                                                                                       \
        if (zp) {                                                                           \
            const u16* vn = xt + ((size_t)(b * NC + (c0) + cc)) * NHW + (size_t)r * NP + ch;\
            *(uint4*)&vh[0] = *(const uint4*)(vn);                                          \
            *(uint4*)&vh[8] = *(const uint4*)(vn + 8);                                      \
        } else {                                                                            \
            const float* vn = x + ((size_t)(b * NC + (c0) + cc)) * NHW + (size_t)r * NP + ch;\
            _Pragma("unroll") for (int e2 = 0; e2 < 4; e2++) {                              \
                float4 vv = *(const float4*)(vn + e2 * 4);                                  \
                vh[e2 * 4 + 0] = f2h(vv.x); vh[e2 * 4 + 1] = f2h(vv.y);                     \
                vh[e2 * 4 + 2] = f2h(vv.z); vh[e2 * 4 + 3] = f2h(vv.w);                     \
            }                                                                               \
        }                                                                                   \
    }

    LOADV(0);
    for (int c0 = 0; c0 < NC; c0 += 64) {
        *(uint4*)&Vl[cc * 136 + ch] = *(uint4*)&vh[0];
        *(uint4*)&Vl[cc * 136 + ch + 8] = *(uint4*)&vh[8];
        __syncthreads();
        if (c0 + 64 < NC) LOADV(c0 + 64);   // hide next tile's HBM latency under MFMA
        f32x4 o[2][2];
#pragma unroll
        for (int mf2 = 0; mf2 < 2; mf2++)
#pragma unroll
            for (int nf2 = 0; nf2 < 2; nf2++) o[mf2][nf2] = 0.0f;
#pragma unroll
        for (int js = 0; js < 4; js++) {
            f16x8 va[2];
#pragma unroll
            for (int mf2 = 0; mf2 < 2; mf2++)
                va[mf2] = *(const f16x8*)&Vl[(wc * 32 + mf2 * 16 + ln) * 136 + js * 32 + g * 8];
#pragma unroll
            for (int mf2 = 0; mf2 < 2; mf2++)
#pragma unroll
                for (int nf2 = 0; nf2 < 2; nf2++)
                    o[mf2][nf2] = __builtin_amdgcn_mfma_f32_16x16x32_f16(va[mf2], bfr[nf2][js], o[mf2][nf2], 0, 0, 0);
        }
        if (zp || WOH) {
            // fp16 path: bounce through Ob (region A) for coalesced uint4 stores
#pragma unroll
            for (int mf2 = 0; mf2 < 2; mf2++)
#pragma unroll
                for (int nf2 = 0; nf2 < 2; nf2++)
#pragma unroll
                    for (int rg = 0; rg < 4; rg++) {
                        int cl = wc * 32 + mf2 * 16 + g * 4 + rg;
                        int ii = wi2 * 32 + nf2 * 16 + ln;
                        Ob[cl * 136 + ii] = f2h(o[mf2][nf2][rg]);
                    }
            __syncthreads();
            {
                int cl = tid >> 3, seg = (tid & 7) * 16;
                u16* dst = (zp ? oht : owh) + ((size_t)(b * NC + c0 + cl)) * NHW + (size_t)r * NP + seg;
                const u16* srcl = &Ob[cl * 136 + seg];
                *(uint4*)dst       = *(const uint4*)srcl;
                *(uint4*)(dst + 8) = *(const uint4*)(srcl + 8);
            }
        } else {
            // fp32 fallback path (scatter)
#pragma unroll
            for (int mf2 = 0; mf2 < 2; mf2++)
#pragma unroll
                for (int nf2 = 0; nf2 < 2; nf2++)
#pragma unroll
                    for (int rg = 0; rg < 4; rg++) {
                        int ci = c0 + wc * 32 + mf2 * 16 + g * 4 + rg;
                        int ii = wi2 * 32 + nf2 * 16 + ln;
                        outw[((size_t)(b * NC + ci)) * NHW + (size_t)r * NP + ii] = o[mf2][nf2][rg];
                    }
        }
        __syncthreads();   // protects Vl and Ob for next stage
    }
#undef LOADV
}

// ---------------- out[plane][h][w] = owh[plane][h][w] + oht[plane][w][h] ----------------
__global__ __launch_bounds__(256) void combine_kernel(const u16* __restrict__ owh,
                                                      const u16* __restrict__ oht,
                                                      float* __restrict__ out) {
    __shared__ u16 ts[32][36];
    int plane = blockIdx.y;
    int tile  = blockIdx.x;
    int h0 = (tile >> 2) * 32, w0 = (tile & 3) * 32;
    int r  = threadIdx.x >> 3;
    int c4 = (threadIdx.x & 7) * 4;
    ushort4 v = *(const ushort4*)(oht + (size_t)plane * NHW + (w0 + r) * NP + h0 + c4);
    ts[r][c4 + 0] = v.x; ts[r][c4 + 1] = v.y; ts[r][c4 + 2] = v.z; ts[r][c4 + 3] = v.w;
    __syncthreads();
    ushort4 a = *(const ushort4*)(owh + (size_t)plane * NHW + (h0 + r) * NP + w0 + c4);
    float4 o;
    o.x = h2f(a.x) + h2f(ts[c4 + 0][r]);
    o.y = h2f(a.y) + h2f(ts[c4 + 1][r]);
    o.z = h2f(a.z) + h2f(ts[c4 + 2][r]);
    o.w = h2f(a.w) + h2f(ts[c4 + 3][r]);
    *(float4*)(out + (size_t)plane * NHW + (h0 + r) * NP + w0 + c4) = o;
}

// ---------------- fallback: out[plane][h][w] += oht[plane][w][h] (fp16 -> fp32 RMW) ----------------
__global__ __launch_bounds__(256) void addtr_kernel(const u16* __restrict__ oht,
                                                    float* __restrict__ out) {
    __shared__ u16 ts[32][36];
    int plane = blockIdx.y;
    int tile  = blockIdx.x;
    int h0 = (tile >> 2) * 32, w0 = (tile & 3) * 32;
    int r  = threadIdx.x >> 3;
    int c4 = (threadIdx.x & 7) * 4;
    ushort4 v = *(const ushort4*)(oht + (size_t)plane * NHW + (w0 + r) * NP + h0 + c4);
    ts[r][c4 + 0] = v.x; ts[r][c4 + 1] = v.y; ts[r][c4 + 2] = v.z; ts[r][c4 + 3] = v.w;
    __syncthreads();
    float* dst = out + (size_t)plane * NHW + (h0 + r) * NP + w0 + c4;
    float4 cur = *(const float4*)dst;
    cur.x += h2f(ts[c4 + 0][r]);
    cur.y += h2f(ts[c4 + 1][r]);
    cur.z += h2f(ts[c4 + 2][r]);
    cur.w += h2f(ts[c4 + 3][r]);
    *(float4*)dst = cur;
}

extern "C" void kernel_launch(void* const* d_in, const int* in_sizes, int n_in,
                              void* d_out, int out_size, void* d_ws, size_t ws_size,
                              hipStream_t stream) {
    const float* x  = (const float*)d_in[0];
    const float* wq = (const float*)d_in[1];
    const float* bq = (const float*)d_in[2];
    const float* wk = (const float*)d_in[3];
    const float* bk = (const float*)d_in[4];
    float* out = (float*)d_out;

    const size_t QKE = (size_t)NB * NHW * NK;  // 16,777,216 elems
    const size_t XE  = (size_t)NB * NC * NHW;  // 67,108,864 elems
    const size_t WHE = (size_t)256 * 512;
    u16* wh  = (u16*)d_ws;
    u16* q   = wh + WHE;
    u16* k   = q + QKE;
    u16* xt  = k + QKE;
    u16* oht = xt + XE;
    u16* owh = oht + XE;
    const size_t need_big = (WHE + 2 * QKE + 3 * XE) * sizeof(u16);  // ~470 MiB
    const bool big = ws_size >= need_big;

    dim3 blk(256);
    dim3 ablk(512);

    // 0. weights -> fp16
    wconv_kernel<<<dim3(256), blk, 0, stream>>>(wq, wk, wh);
    // 1. x -> xt fp16 transposed [b][c][w][h]
    convtr_kernel<<<dim3(16, NB * NC), blk, 0, stream>>>(x, xt);
    // 2. fused q,k projection (MFMA v3), pixel-major fp16
    proj_kernel<<<dim3(NHW / 64, NB), blk, 0, stream>>>(x, wh, bq, bk, q, k);

    if (big) {
        // 3. merged W+H attention, 512 threads, coalesced O stores
        attn_kernel<1><<<dim3(NP, NB, 2), ablk, 0, stream>>>(q, k, x, xt, owh, oht, out);
        // 4. out = owh + oht^T
        combine_kernel<<<dim3(16, NB * NC), blk, 0, stream>>>(owh, oht, out);
    } else {
        // fallback: W-pass writes out fp32 directly, then RMW-add of oht^T
        attn_kernel<0><<<dim3(NP, NB, 2), ablk, 0, stream>>>(q, k, x, xt, owh, oht, out);
        addtr_kernel<<<dim3(16, NB * NC), blk, 0, stream>>>(oht, out);
    }
}

// Round 21
// 451.153 us; speedup vs baseline: 1.0331x; 1.0008x over previous
//
#include <hip/hip_runtime.h>
#include <hip/hip_fp16.h>

#define NB 8
#define NC 512
#define NK 128   // key_dim C2
#define NP 128   // positions per attention row (H = W = 128)
#define NHW 16384

typedef unsigned short u16;
typedef unsigned int u32;
typedef float f32x4 __attribute__((ext_vector_type(4)));
typedef _Float16 f16x8 __attribute__((ext_vector_type(8)));

__device__ __forceinline__ u16 f2h(float f) { return __half_as_ushort(__float2half(f)); }
__device__ __forceinline__ float h2f(u16 u) { return __half2float(__ushort_as_half(u)); }

// LDS-visibility barrier WITHOUT vmcnt drain: global loads/stores stay in flight.
// (__syncthreads() emits s_waitcnt vmcnt(0) lgkmcnt(0); this emits only lgkmcnt(0).)
#define BARL()                                                  \
    do {                                                        \
        asm volatile("s_waitcnt lgkmcnt(0)" ::: "memory");      \
        __builtin_amdgcn_s_barrier();                           \
    } while (0)

// ---------------- weights fp32 -> fp16, concatenated [wq;wk] row-major ----------------
__global__ __launch_bounds__(256) void wconv_kernel(const float* __restrict__ wq,
                                                    const float* __restrict__ wk,
                                                    u16* __restrict__ wh) {
    int row = blockIdx.x;  // 0..255
    const float* src = (row < 128) ? (wq + (size_t)row * NC) : (wk + (size_t)(row - 128) * NC);
    int t = threadIdx.x;
    float2 v = *(const float2*)(src + t * 2);
    ushort2 o; o.x = f2h(v.x); o.y = f2h(v.y);
    *(ushort2*)(wh + (size_t)row * NC + t * 2) = o;
}

// ---------------- x fp32 [plane][h][w] -> xt fp16 [plane][w][h] ----------------
__global__ __launch_bounds__(256) void convtr_kernel(const float* __restrict__ x,
                                                     u16* __restrict__ xt) {
    __shared__ u16 ts[32][36];
    int plane = blockIdx.y;
    int tile  = blockIdx.x;
    int h0 = (tile >> 2) * 32, w0 = (tile & 3) * 32;
    const float* ip = x + (size_t)plane * NHW;
    u16* op = xt + (size_t)plane * NHW;
    int r  = threadIdx.x >> 3;
    int c4 = (threadIdx.x & 7) * 4;
    float4 v = *(const float4*)(ip + (h0 + r) * NP + w0 + c4);
    ts[r][c4 + 0] = f2h(v.x); ts[r][c4 + 1] = f2h(v.y);
    ts[r][c4 + 2] = f2h(v.z); ts[r][c4 + 3] = f2h(v.w);
    __syncthreads();
    ushort4 o;
    o.x = ts[c4 + 0][r]; o.y = ts[c4 + 1][r]; o.z = ts[c4 + 2][r]; o.w = ts[c4 + 3][r];
    *(ushort4*)(op + (w0 + r) * NP + h0 + c4) = o;
}

// ---------------- fused q+k projection via MFMA (v3, unchanged) ----------------
#define XROW 40   // u16 stride of one p-row (80 B, 16B-aligned)
__device__ __forceinline__ int xt2_off(int p, int cw) {
    int sw = ((p >> 3) & 3) << 2;
    return p * XROW + 2 * (cw ^ sw);
}

__global__ __launch_bounds__(256, 3) void proj_kernel(const float* __restrict__ x,
                                                      const u16* __restrict__ wh,
                                                      const float* __restrict__ bq,
                                                      const float* __restrict__ bk,
                                                      u16* __restrict__ q,
                                                      u16* __restrict__ k) {
    __shared__ __align__(16) u16 smem[9216];
    int b  = blockIdx.y;
    int p0 = blockIdx.x * 64;
    int tid = threadIdx.x;
    int lane = tid & 63, w = tid >> 6;
    int ln = lane & 15, g = lane >> 4;

    float biasv[4];
#pragma unroll
    for (int nf = 0; nf < 4; nf++) {
        int oc = w * 64 + nf * 16 + ln;
        biasv[nf] = (oc < 128) ? bq[oc] : bk[oc - 128];
    }

    f32x4 acc[4][4];
#pragma unroll
    for (int mf = 0; mf < 4; mf++)
#pragma unroll
        for (int nf = 0; nf < 4; nf++) acc[mf][nf] = 0.0f;

    int si  = tid >> 4;          // 0..15
    int spx = (tid & 15) * 4;

#define STAGE(buf, c0)                                                                  \
    {                                                                                   \
        const float* xa = x + ((size_t)(b * NC + (c0) + 2 * si)) * NHW + p0 + spx;      \
        const float* xb = xa + NHW;                                                     \
        float4 a0 = *(const float4*)xa;                                                 \
        float4 b0 = *(const float4*)xb;                                                 \
        float av[4] = {a0.x, a0.y, a0.z, a0.w};                                         \
        float bv[4] = {b0.x, b0.y, b0.z, b0.w};                                         \
        _Pragma("unroll") for (int j = 0; j < 4; j++) {                                 \
            ushort2 pk;                                                                 \
            pk.x = f2h(av[j]); pk.y = f2h(bv[j]);                                       \
            *(ushort2*)&smem[(buf) * 2560 + xt2_off(spx + j, si)] = pk;                 \
        }                                                                               \
    }

    STAGE(0, 0);
    __syncthreads();
    for (int t = 0; t < 16; ++t) {
        int c0 = t * 32;
        if (t < 15) STAGE((t + 1) & 1, c0 + 32);
        f16x8 bf[4];
#pragma unroll
        for (int nf = 0; nf < 4; nf++)
            bf[nf] = *(const f16x8*)&wh[((size_t)(w * 64 + nf * 16 + ln)) * NC + c0 + g * 8];
        f16x8 af[4];
#pragma unroll
        for (int mf = 0; mf < 4; mf++)
            af[mf] = *(const f16x8*)&smem[(t & 1) * 2560 + xt2_off(mf * 16 + ln, g * 4)];
#pragma unroll
        for (int mf = 0; mf < 4; mf++)
#pragma unroll
            for (int nf = 0; nf < 4; nf++)
                acc[mf][nf] = __builtin_amdgcn_mfma_f32_16x16x32_f16(af[mf], bf[nf], acc[mf][nf], 0, 0, 0);
        __syncthreads();
    }
#undef STAGE

#pragma unroll
    for (int pass = 0; pass < 2; pass++) {
        if ((w >> 1) == pass) {
            int colbase = (w & 1) * 64;
#pragma unroll
            for (int mf = 0; mf < 4; mf++)
#pragma unroll
                for (int nf = 0; nf < 4; nf++)
#pragma unroll
                    for (int rg = 0; rg < 4; rg++) {
                        int p = mf * 16 + g * 4 + rg;
                        smem[p * 136 + colbase + nf * 16 + ln] = f2h(acc[mf][nf][rg] + biasv[nf]);
                    }
        }
        __syncthreads();
        {
            int p = tid >> 2, seg = tid & 3;
            u16* dst = (pass == 0 ? q : k) + ((size_t)(b * NHW + p0 + p)) * NK + seg * 32;
            const u16* srcl = &smem[p * 136 + seg * 32];
            *(uint4*)(dst)     = *(const uint4*)(srcl);
            *(uint4*)(dst + 8) = *(const uint4*)(srcl + 8);
            *(uint4*)(dst + 16) = *(const uint4*)(srcl + 16);
            *(uint4*)(dst + 24) = *(const uint4*)(srcl + 24);
        }
        __syncthreads();
    }
}

// ---------------- merged axis attention — 512 threads, counted-wait barriers (no vmcnt drain) ----------------
// zp=0: W-pass — r=h, Q/K rows contiguous, V = x fp32 (cvt), out = owh fp16 (WOH=1) or outw fp32
// zp=1: H-pass — r=w, Q/K rows strided,   V = xt fp16,       out = oht fp16
// E: wave (wj=w>>2, wi=w&3) owns 64j x 32i -> e[4][2]. PV: wave (wc=w>>2, wi2=w&3) owns 32c x 32i.
// All attn barriers are BARL(): lgkmcnt(0)+raw s_barrier — V-prefetch and output stores remain
// in flight across barriers (T3/T4 mechanism); compiler inserts exact vmcnt waits at vh uses.
template <int WOH>
__global__ __launch_bounds__(512) void attn_kernel(const u16* __restrict__ q,
                                                   const u16* __restrict__ k,
                                                   const float* __restrict__ x,
                                                   const u16* __restrict__ xt,
                                                   u16* __restrict__ owh,
                                                   u16* __restrict__ oht,
                                                   float* __restrict__ outw) {
    __shared__ __align__(16) u16 smem[2 * 128 * 136];
    __shared__ float redmax[256];
    __shared__ float redsum[256];
    u16* Ks = smem;
    u16* Qs = smem + 128 * 136;
    u16* Al = smem;
    u16* Vl = smem + 128 * 136;
    u16* Ob = smem;              // PV output bounce: overlays Al (dead after bfr hoist)

    int r = blockIdx.x, b = blockIdx.y;
    int zp = blockIdx.z;   // 0 = W-pass, 1 = H-pass
    int tid = threadIdx.x;
    int lane = tid & 63, w = tid >> 6;
    int ln = lane & 15, g = lane >> 4;

    const size_t base = zp ? ((size_t)b * NHW + r) * NK : ((size_t)b * NHW + (size_t)r * NP) * NK;
    const int qrs = zp ? NP * NK : NK;

    // stage Q,K position-major [j][c]: 512 threads, 64B per matrix each
    {
        int j = tid >> 2, hf = tid & 3;
        const u16* qp2 = q + base + (size_t)j * qrs + hf * 32;
        const u16* kp2 = k + base + (size_t)j * qrs + hf * 32;
#pragma unroll
        for (int e = 0; e < 4; e++) {
            *(uint4*)&Qs[j * 136 + hf * 32 + e * 8] = *(const uint4*)(qp2 + e * 8);
            *(uint4*)&Ks[j * 136 + hf * 32 + e * 8] = *(const uint4*)(kp2 + e * 8);
        }
    }
    BARL();

    // ---- E^T: wave (wj, wi), tile 64j x 32i ----
    int wj = w >> 2, wi = w & 3;
    f32x4 e[4][2];
#pragma unroll
    for (int mf = 0; mf < 4; mf++)
#pragma unroll
        for (int nf = 0; nf < 2; nf++) e[mf][nf] = 0.0f;
#pragma unroll
    for (int ks = 0; ks < 4; ks++) {
        f16x8 qa[4], kb[2];
#pragma unroll
        for (int mf = 0; mf < 4; mf++)
            qa[mf] = *(const f16x8*)&Qs[(wj * 64 + mf * 16 + ln) * 136 + ks * 32 + g * 8];
#pragma unroll
        for (int nf = 0; nf < 2; nf++)
            kb[nf] = *(const f16x8*)&Ks[(wi * 32 + nf * 16 + ln) * 136 + ks * 32 + g * 8];
#pragma unroll
        for (int mf = 0; mf < 4; mf++)
#pragma unroll
            for (int nf = 0; nf < 2; nf++)
                e[mf][nf] = __builtin_amdgcn_mfma_f32_16x16x32_f16(qa[mf], kb[nf], e[mf][nf], 0, 0, 0);
    }

    // ---- softmax over j; lane's i columns: i = wi*32 + nf*16 + ln ----
    float pm[2];
#pragma unroll
    for (int nf = 0; nf < 2; nf++) {
        pm[nf] = -3.0e38f;
#pragma unroll
        for (int mf = 0; mf < 4; mf++)
#pragma unroll
            for (int rg = 0; rg < 4; rg++) pm[nf] = fmaxf(pm[nf], e[mf][nf][rg]);
        pm[nf] = fmaxf(pm[nf], __shfl_xor(pm[nf], 16));
        pm[nf] = fmaxf(pm[nf], __shfl_xor(pm[nf], 32));
    }
    if (g == 0) {
#pragma unroll
        for (int nf = 0; nf < 2; nf++) redmax[wj * 128 + wi * 32 + nf * 16 + ln] = pm[nf];
    }
    BARL();
    float fm[2];
#pragma unroll
    for (int nf = 0; nf < 2; nf++) {
        int i = wi * 32 + nf * 16 + ln;
        fm[nf] = fmaxf(redmax[i], redmax[128 + i]);
    }
    float ps[2] = {0.f, 0.f};
#pragma unroll
    for (int mf = 0; mf < 4; mf++)
#pragma unroll
        for (int nf = 0; nf < 2; nf++)
#pragma unroll
            for (int rg = 0; rg < 4; rg++) {
                float v = __expf(e[mf][nf][rg] - fm[nf]);
                e[mf][nf][rg] = v;
                ps[nf] += v;
            }
#pragma unroll
    for (int nf = 0; nf < 2; nf++) {
        ps[nf] += __shfl_xor(ps[nf], 16);
        ps[nf] += __shfl_xor(ps[nf], 32);
    }
    if (g == 0) {
#pragma unroll
        for (int nf = 0; nf < 2; nf++) redsum[wj * 128 + wi * 32 + nf * 16 + ln] = ps[nf];
    }
    BARL();
    float ivs[2];
#pragma unroll
    for (int nf = 0; nf < 2; nf++) {
        int i = wi * 32 + nf * 16 + ln;
        ivs[nf] = 1.0f / (redsum[i] + redsum[128 + i]);
    }
    // pack A fp16 into Al[i][j] (region A = Qs; all cross-wave Qs reads completed before the
    // redmax barrier's lgkmcnt(0), so overwriting is safe)
#pragma unroll
    for (int mf = 0; mf < 4; mf++)
#pragma unroll
        for (int nf = 0; nf < 2; nf++) {
            ushort4 pk;
            pk.x = f2h(e[mf][nf][0] * ivs[nf]);
            pk.y = f2h(e[mf][nf][1] * ivs[nf]);
            pk.z = f2h(e[mf][nf][2] * ivs[nf]);
            pk.w = f2h(e[mf][nf][3] * ivs[nf]);
            *(ushort4*)&Al[(wi * 32 + nf * 16 + ln) * 136 + wj * 64 + mf * 16 + g * 4] = pk;
        }
    BARL();

    // ---- PV: wave (wc, wi2) owns 32c x 32i per c-tile of 64 ----
    int wc = w >> 2, wi2 = w & 3;
    f16x8 bfr[2][4];
#pragma unroll
    for (int nf2 = 0; nf2 < 2; nf2++)
#pragma unroll
        for (int js = 0; js < 4; js++)
            bfr[nf2][js] = *(const f16x8*)&Al[(wi2 * 32 + nf2 * 16 + ln) * 136 + js * 32 + g * 8];
    BARL();   // all bfr ds_reads of Al drained -> region A free for Ob

    int cc = tid >> 3, ch = (tid & 7) * 16;   // 64 rows x 128 cols, 16 u16/thread
    u16 vh[16];
#define LOADV(c0)                                                                           \
    {                                                                                       \
        if (zp) {                                                                           \
            const u16* vn = xt + ((size_t)(b * NC + (c0) + cc)) * NHW + (size_t)r * NP + ch;\
            *(uint4*)&vh[0] = *(const uint4*)(vn);                                          \
            *(uint4*)&vh[8] = *(const uint4*)(vn + 8);                                      \
        } else {                                                                            \
            const float* vn = x + ((size_t)(b * NC + (c0) + cc)) * NHW + (size_t)r * NP + ch;\
            _Pragma("unroll") for (int e2 = 0; e2 < 4; e2++) {                              \
                float4 vv = *(const float4*)(vn + e2 * 4);                                  \
                vh[e2 * 4 + 0] = f2h(vv.x); vh[e2 * 4 + 1] = f2h(vv.y);                     \
                vh[e2 * 4 + 2] = f2h(vv.z); vh[e2 * 4 + 3] = f2h(vv.w);                     \
            }                                                                               \
        }                                                                                   \
    }

    LOADV(0);
    for (int c0 = 0; c0 < NC; c0 += 64) {
        *(uint4*)&Vl[cc * 136 + ch] = *(uint4*)&vh[0];
        *(uint4*)&Vl[cc * 136 + ch + 8] = *(uint4*)&vh[8];
        BARL();
        if (c0 + 64 < NC) LOADV(c0 + 64);   // stays in flight across the next barriers
        f32x4 o[2][2];
#pragma unroll
        for (int mf2 = 0; mf2 < 2; mf2++)
#pragma unroll
            for (int nf2 = 0; nf2 < 2; nf2++) o[mf2][nf2] = 0.0f;
#pragma unroll
        for (int js = 0; js < 4; js++) {
            f16x8 va[2];
#pragma unroll
            for (int mf2 = 0; mf2 < 2; mf2++)
                va[mf2] = *(const f16x8*)&Vl[(wc * 32 + mf2 * 16 + ln) * 136 + js * 32 + g * 8];
#pragma unroll
            for (int mf2 = 0; mf2 < 2; mf2++)
#pragma unroll
                for (int nf2 = 0; nf2 < 2; nf2++)
                    o[mf2][nf2] = __builtin_amdgcn_mfma_f32_16x16x32_f16(va[mf2], bfr[nf2][js], o[mf2][nf2], 0, 0, 0);
        }
        if (zp || WOH) {
            // fp16 path: bounce through Ob (region A) for coalesced uint4 stores
#pragma unroll
            for (int mf2 = 0; mf2 < 2; mf2++)
#pragma unroll
                for (int nf2 = 0; nf2 < 2; nf2++)
#pragma unroll
                    for (int rg = 0; rg < 4; rg++) {
                        int cl = wc * 32 + mf2 * 16 + g * 4 + rg;
                        int ii = wi2 * 32 + nf2 * 16 + ln;
                        Ob[cl * 136 + ii] = f2h(o[mf2][nf2][rg]);
                    }
            BARL();
            {
                int cl = tid >> 3, seg = (tid & 7) * 16;
                u16* dst = (zp ? oht : owh) + ((size_t)(b * NC + c0 + cl)) * NHW + (size_t)r * NP + seg;
                const u16* srcl = &Ob[cl * 136 + seg];
                *(uint4*)dst       = *(const uint4*)srcl;
                *(uint4*)(dst + 8) = *(const uint4*)(srcl + 8);
            }
        } else {
            // fp32 fallback path (scatter)
#pragma unroll
            for (int mf2 = 0; mf2 < 2; mf2++)
#pragma unroll
                for (int nf2 = 0; nf2 < 2; nf2++)
#pragma unroll
                    for (int rg = 0; rg < 4; rg++) {
                        int ci = c0 + wc * 32 + mf2 * 16 + g * 4 + rg;
                        int ii = wi2 * 32 + nf2 * 16 + ln;
                        outw[((size_t)(b * NC + ci)) * NHW + (size_t)r * NP + ii] = o[mf2][nf2][rg];
                    }
        }
        BARL();   // protects Vl (reads drained above) and Ob for next stage; stores keep draining
    }
#undef LOADV
}

// ---------------- out[plane][h][w] = owh[plane][h][w] + oht[plane][w][h] ----------------
__global__ __launch_bounds__(256) void combine_kernel(const u16* __restrict__ owh,
                                                      const u16* __restrict__ oht,
                                                      float* __restrict__ out) {
    __shared__ u16 ts[32][36];
    int plane = blockIdx.y;
    int tile  = blockIdx.x;
    int h0 = (tile >> 2) * 32, w0 = (tile & 3) * 32;
    int r  = threadIdx.x >> 3;
    int c4 = (threadIdx.x & 7) * 4;
    ushort4 v = *(const ushort4*)(oht + (size_t)plane * NHW + (w0 + r) * NP + h0 + c4);
    ts[r][c4 + 0] = v.x; ts[r][c4 + 1] = v.y; ts[r][c4 + 2] = v.z; ts[r][c4 + 3] = v.w;
    __syncthreads();
    ushort4 a = *(const ushort4*)(owh + (size_t)plane * NHW + (h0 + r) * NP + w0 + c4);
    float4 o;
    o.x = h2f(a.x) + h2f(ts[c4 + 0][r]);
    o.y = h2f(a.y) + h2f(ts[c4 + 1][r]);
    o.z = h2f(a.z) + h2f(ts[c4 + 2][r]);
    o.w = h2f(a.w) + h2f(ts[c4 + 3][r]);
    *(float4*)(out + (size_t)plane * NHW + (h0 + r) * NP + w0 + c4) = o;
}

// ---------------- fallback: out[plane][h][w] += oht[plane][w][h] (fp16 -> fp32 RMW) ----------------
__global__ __launch_bounds__(256) void addtr_kernel(const u16* __restrict__ oht,
                                                    float* __restrict__ out) {
    __shared__ u16 ts[32][36];
    int plane = blockIdx.y;
    int tile  = blockIdx.x;
    int h0 = (tile >> 2) * 32, w0 = (tile & 3) * 32;
    int r  = threadIdx.x >> 3;
    int c4 = (threadIdx.x & 7) * 4;
    ushort4 v = *(const ushort4*)(oht + (size_t)plane * NHW + (w0 + r) * NP + h0 + c4);
    ts[r][c4 + 0] = v.x; ts[r][c4 + 1] = v.y; ts[r][c4 + 2] = v.z; ts[r][c4 + 3] = v.w;
    __syncthreads();
    float* dst = out + (size_t)plane * NHW + (h0 + r) * NP + w0 + c4;
    float4 cur = *(const float4*)dst;
    cur.x += h2f(ts[c4 + 0][r]);
    cur.y += h2f(ts[c4 + 1][r]);
    cur.z += h2f(ts[c4 + 2][r]);
    cur.w += h2f(ts[c4 + 3][r]);
    *(float4*)dst = cur;
}

extern "C" void kernel_launch(void* const* d_in, const int* in_sizes, int n_in,
                              void* d_out, int out_size, void* d_ws, size_t ws_size,
                              hipStream_t stream) {
    const float* x  = (const float*)d_in[0];
    const float* wq = (const float*)d_in[1];
    const float* bq = (const float*)d_in[2];
    const float* wk = (const float*)d_in[3];
    const float* bk = (const float*)d_in[4];
    float* out = (float*)d_out;

    const size_t QKE = (size_t)NB * NHW * NK;  // 16,777,216 elems
    const size_t XE  = (size_t)NB * NC * NHW;  // 67,108,864 elems
    const size_t WHE = (size_t)256 * 512;
    u16* wh  = (u16*)d_ws;
    u16* q   = wh + WHE;
    u16* k   = q + QKE;
    u16* xt  = k + QKE;
    u16* oht = xt + XE;
    u16* owh = oht + XE;
    const size_t need_big = (WHE + 2 * QKE + 3 * XE) * sizeof(u16);  // ~470 MiB
    const bool big = ws_size >= need_big;

    dim3 blk(256);
    dim3 ablk(512);

    // 0. weights -> fp16
    wconv_kernel<<<dim3(256), blk, 0, stream>>>(wq, wk, wh);
    // 1. x -> xt fp16 transposed [b][c][w][h]
    convtr_kernel<<<dim3(16, NB * NC), blk, 0, stream>>>(x, xt);
    // 2. fused q,k projection (MFMA v3), pixel-major fp16
    proj_kernel<<<dim3(NHW / 64, NB), blk, 0, stream>>>(x, wh, bq, bk, q, k);

    if (big) {
        // 3. merged W+H attention, 512 threads, no-drain barriers
        attn_kernel<1><<<dim3(NP, NB, 2), ablk, 0, stream>>>(q, k, x, xt, owh, oht, out);
        // 4. out = owh + oht^T
        combine_kernel<<<dim3(16, NB * NC), blk, 0, stream>>>(owh, oht, out);
    } else {
        // fallback: W-pass writes out fp32 directly, then RMW-add of oht^T
        attn_kernel<0><<<dim3(NP, NB, 2), ablk, 0, stream>>>(q, k, x, xt, owh, oht, out);
        addtr_kernel<<<dim3(16, NB * NC), blk, 0, stream>>>(oht, out);
    }
}